// Round 11
// baseline (537.161 us; speedup 1.0000x reference)
//
#include <hip/hip_runtime.h>

#define BQ 4096
#define NS 5

typedef __attribute__((ext_vector_type(8))) short bf16x8;
typedef __attribute__((ext_vector_type(4))) float f32x4;
typedef unsigned short ushortT;

// ---------------- ws layout (float offsets) ----------------
#define WS_QNB    0          // 4096*256 f32
#define WS_Z      1048576    // 4096*256 f32
#define WS_QG     2097152    // 4096*256 f32
#define WS_WHH2   3145728    // 1024*512 bf16 = 262144 f32-units (reuses old XW region)
#define WS_CBUF   5242880    // (unused)
#define WS_XS     6291456    // 8256*256 bf16 = 1056768 f32-units
#define WS_H1B    7348224    // 4096*512 bf16 = 524288
#define WS_ABF    7872512    // 4096*256 bf16 = 262144 (Xq / Qgb)
#define WS_HB1    8134656    // (unused)
#define WS_P1B    8396800    // 512*256 bf16 = 65536
#define WS_P2B    8462336    // 256*512 bf16
#define WS_WIHB   8527872    // 1024*256 bf16 = 131072
#define WS_WHHB   8658944    // (unused)
#define WS_GWB    8790016    // 128*256 bf16 = 16384
#define WS_SNB    8806400    // 5*256
#define WS_H1G    8807680    // 5*512
#define WS_ZB     8810240    // 5*256
#define WS_SG     8811520    // 256
#define WS_SN     8811776    // 256
#define WS_SGB    8812032    // 256 bf16 (sg rounded, LSTM r-input)
#define WS_BL     8813056    // 1024
#define WS_EMB16  8814080    // 200001*128 bf16 = 12800064 f32-units (optional)
#define EMB_ELEMS 25600128   // 200001*128

__device__ __forceinline__ float wave_allreduce(float v) {
#pragma unroll
  for (int off = 32; off > 0; off >>= 1) v += __shfl_xor(v, off, 64);
  return v;
}
__device__ __forceinline__ float block_allreduce(float v, float* buf) {
  v = wave_allreduce(v);
  __syncthreads();
  if ((threadIdx.x & 63) == 0) buf[threadIdx.x >> 6] = v;
  __syncthreads();
  return buf[0] + buf[1] + buf[2] + buf[3];
}
__device__ __forceinline__ float sigm(float x) { return 1.0f / (1.0f + expf(-x)); }
__device__ __forceinline__ ushortT f2bf(float f) {
  unsigned int u = __float_as_uint(f);
  unsigned int r = (u + 0x7fffu + ((u >> 16) & 1u)) >> 16;
  return (ushortT)r;
}
__device__ __forceinline__ float bf2f(ushortT u) {
  return __uint_as_float(((unsigned int)u) << 16);
}
__device__ __forceinline__ float dot4(float4 a, float4 b) {
  return a.x * b.x + a.y * b.y + a.z * b.z + a.w * b.w;
}

// ---------------- prep: emb->bf16 (optional) + weight pack (whh2 = FULL 512 cols) ----------------
__global__ __launch_bounds__(256) void k_prep(
    const float* __restrict__ emb, ushortT* __restrict__ emb16, int doEmb,
    const float* __restrict__ w_ih, const float* __restrict__ w_hh,
    const float* __restrict__ p1w, const float* __restrict__ p2w,
    const float* __restrict__ gcn_w,
    const float* __restrict__ b_ih, const float* __restrict__ b_hh,
    ushortT* __restrict__ p1b16, ushortT* __restrict__ p2b16,
    ushortT* __restrict__ wihb, ushortT* __restrict__ whh2,
    ushortT* __restrict__ gwb, float* __restrict__ bL) {
  const int gid = blockIdx.x * 256 + threadIdx.x;
  const int stride = gridDim.x * 256;
  if (doEmb) {
    const float4* e4 = (const float4*)emb;
    ushort4* o4 = (ushort4*)emb16;
    for (int i = gid; i < EMB_ELEMS / 4; i += stride) {
      float4 v = e4[i];
      ushort4 u;
      u.x = f2bf(v.x); u.y = f2bf(v.y); u.z = f2bf(v.z); u.w = f2bf(v.w);
      o4[i] = u;
    }
  }
  for (int i = gid; i < 131072; i += stride) p1b16[i] = f2bf(p1w[i]);
  for (int i = gid; i < 131072; i += stride) p2b16[i] = f2bf(p2w[i]);
  for (int i = gid; i < 262144; i += stride) {
    int n = i >> 8, k = i & 255;
    int j = (n >> 2) + 512 * (n & 3);
    wihb[i] = f2bf(w_ih[j * 256 + k]);
  }
  for (int i = gid; i < 524288; i += stride) {
    int n = i >> 9, k = i & 511;
    int j = (n >> 2) + 512 * (n & 3);
    whh2[i] = f2bf(w_hh[j * 512 + k]);
  }
  for (int i = gid; i < 32768; i += stride) gwb[i] = f2bf(gcn_w[i]);
  for (int i = gid; i < 1024; i += stride) {
    int j = (i >> 2) + 512 * (i & 3);
    bL[i] = b_ih[j] + b_hh[j];
  }
}

// ---------------- gather+sum from bf16 table: 16 row-loads in flight ----------------
__global__ __launch_bounds__(256) void k_gather16(
    const int* __restrict__ qlc, const int* __restrict__ qrc,
    const int* __restrict__ slc, const int* __restrict__ src_,
    const ushortT* __restrict__ emb16, ushortT* __restrict__ XS) {
  const int r = blockIdx.x;
  const int b = r >> 1, side = r & 1;
  const int t = threadIdx.x;
  const int* cg2;
  if (b < BQ) cg2 = (side ? qrc : qlc) + (size_t)b * 128;
  else        cg2 = (side ? src_ : slc) + (size_t)(b - BQ) * 128;
  __shared__ int connS[128];
  __shared__ __align__(16) float part[8][132];
  if (t < 128) connS[t] = cg2[t];
  __syncthreads();
  const int s = t >> 5, l = t & 31;
  const ushort4* e2 = (const ushort4*)emb16;
  float4 acc = make_float4(0.f, 0.f, 0.f, 0.f);
  int im[16];
#pragma unroll
  for (int k = 0; k < 16; k++) im[k] = connS[k * 8 + s];
  ushort4 v[16];
#pragma unroll
  for (int k = 0; k < 16; k++) v[k] = e2[(size_t)im[k] * 32 + l];
#pragma unroll
  for (int k = 0; k < 16; k++) {
    acc.x += bf2f(v[k].x); acc.y += bf2f(v[k].y);
    acc.z += bf2f(v[k].z); acc.w += bf2f(v[k].w);
  }
  *(float4*)&part[s][l * 4] = acc;
  __syncthreads();
  const int hf = t >> 7, dd = t & 127;
  float sum = part[hf][dd] + part[2 + hf][dd] + part[4 + hf][dd] + part[6 + hf][dd];
  XS[(size_t)r * 256 + t] = f2bf(sum);
}

// ---------------- fallback gather from fp32 table (verified path) ----------------
__global__ __launch_bounds__(256) void k_gather32(
    const int* __restrict__ qlc, const int* __restrict__ qrc,
    const int* __restrict__ slc, const int* __restrict__ src_,
    const float* __restrict__ emb, ushortT* __restrict__ XS) {
  const int r = blockIdx.x;
  const int b = r >> 1, side = r & 1;
  const int t = threadIdx.x;
  const int* cg2;
  if (b < BQ) cg2 = (side ? qrc : qlc) + (size_t)b * 128;
  else        cg2 = (side ? src_ : slc) + (size_t)(b - BQ) * 128;
  __shared__ int connS[128];
  __shared__ __align__(16) float part[8][132];
  if (t < 128) connS[t] = cg2[t];
  __syncthreads();
  const int s = t >> 5, l = t & 31;
  const float4* emb4 = (const float4*)emb;
  float4 acc = make_float4(0.f, 0.f, 0.f, 0.f);
#pragma unroll
  for (int kb = 0; kb < 2; kb++) {
    int im[8];
#pragma unroll
    for (int k = 0; k < 8; k++) im[k] = connS[(kb * 8 + k) * 8 + s];
    float4 v[8];
#pragma unroll
    for (int k = 0; k < 8; k++) v[k] = emb4[(size_t)im[k] * 32 + l];
#pragma unroll
    for (int k = 0; k < 8; k++) {
      acc.x += v[k].x; acc.y += v[k].y; acc.z += v[k].z; acc.w += v[k].w;
    }
  }
  *(float4*)&part[s][l * 4] = acc;
  __syncthreads();
  const int hf = t >> 7, dd = t & 127;
  float sum = part[hf][dd] + part[2 + hf][dd] + part[4 + hf][dd] + part[6 + hf][dd];
  XS[(size_t)r * 256 + t] = f2bf(sum);
}

// ---------------- GCN matvec as MFMA GEMM + tanh/deg epilogue (verified R7) ----------------
__global__ __launch_bounds__(256) void k_gcn(
    const ushortT* __restrict__ XS, const ushortT* __restrict__ gwb,
    const float* __restrict__ gcn_bias,
    const int* __restrict__ qld, const int* __restrict__ qrd,
    const int* __restrict__ sld, const int* __restrict__ srd,
    float* __restrict__ qnb, float* __restrict__ snb, ushortT* __restrict__ xq) {
  __shared__ short As[64 * 40];
  __shared__ short Bs[128 * 40];
  __shared__ int degl[32], degr[32];
  const int t = threadIdx.x;
  const int row0 = blockIdx.x * 64;
  if (t < 32) {
    int b = (row0 >> 1) + t;
    int dl = 1, dr = 1;
    if (b < BQ) { dl = qld[b]; dr = qrd[b]; }
    else if (b < BQ + NS) { dl = sld[b - BQ]; dr = srd[b - BQ]; }
    degl[t] = (dl > 0) ? dl : 1;
    degr[t] = (dr > 0) ? dr : 1;
  }
  const int wave = t >> 6, lane = t & 63;
  const int wm = wave >> 1, wn = wave & 1, quad = lane >> 4, mr = lane & 15;
  f32x4 acc[2][4];
#pragma unroll
  for (int mi = 0; mi < 2; mi++)
#pragma unroll
    for (int ni = 0; ni < 4; ni++) acc[mi][ni] = (f32x4){0.f, 0.f, 0.f, 0.f};
  const int arow = t >> 2, akc = t & 3;
  for (int k0 = 0; k0 < 256; k0 += 32) {
    float4 av = *(const float4*)(XS + (size_t)(row0 + arow) * 256 + k0 + akc * 8);
    float4 bv0 = *(const float4*)(gwb + (size_t)arow * 256 + k0 + akc * 8);
    float4 bv1 = *(const float4*)(gwb + (size_t)(64 + arow) * 256 + k0 + akc * 8);
    __syncthreads();
    *(float4*)&As[arow * 40 + akc * 8] = av;
    *(float4*)&Bs[arow * 40 + akc * 8] = bv0;
    *(float4*)&Bs[(64 + arow) * 40 + akc * 8] = bv1;
    __syncthreads();
    bf16x8 af[2], bfr[4];
#pragma unroll
    for (int mi = 0; mi < 2; mi++)
      af[mi] = *(const bf16x8*)&As[(wm * 32 + mi * 16 + mr) * 40 + quad * 8];
#pragma unroll
    for (int ni = 0; ni < 4; ni++)
      bfr[ni] = *(const bf16x8*)&Bs[(wn * 64 + ni * 16 + mr) * 40 + quad * 8];
#pragma unroll
    for (int mi = 0; mi < 2; mi++)
#pragma unroll
      for (int ni = 0; ni < 4; ni++)
        acc[mi][ni] = __builtin_amdgcn_mfma_f32_16x16x32_bf16(af[mi], bfr[ni], acc[mi][ni], 0, 0, 0);
  }
#pragma unroll
  for (int mi = 0; mi < 2; mi++) {
#pragma unroll
    for (int ni = 0; ni < 4; ni++) {
      const int col = wn * 64 + ni * 16 + mr;
      const int rb = row0 + wm * 32 + mi * 16 + quad * 4;
      const float bs = 64.0f * gcn_bias[col];
#pragma unroll
      for (int reg = 0; reg < 4; reg++) {
        const int row = rb + reg;
        const int b = row >> 1, side = row & 1;
        if (b >= BQ + NS) continue;
        const int li = (row >> 1) - (row0 >> 1);
        const int deg = side ? degr[li] : degl[li];
        float val = tanhf((acc[mi][ni][reg] + bs) / (float)deg);
        if (b < BQ) {
          const size_t o = (size_t)b * 256 + side * 128 + col;
          qnb[o] = val;
          xq[o] = f2bf(val);
        } else {
          snb[(size_t)(b - BQ) * 256 + side * 128 + col] = val;
        }
      }
    }
  }
}

// ---------------- query proj1 GEMM + sup1 (verified R7) ----------------
__global__ __launch_bounds__(256) void k_proj1(
    const ushortT* __restrict__ A, const ushortT* __restrict__ B,
    const float* __restrict__ bias, ushortT* __restrict__ outb,
    const float* __restrict__ snb, const float* __restrict__ p1w,
    const float* __restrict__ p1b, float* __restrict__ h1g) {
  __shared__ short As[64 * 40];
  __shared__ short Bs[128 * 40];
  const int t = threadIdx.x;
  if (blockIdx.x >= 256) {
    const int w = (blockIdx.x - 256) * 4 + (t >> 6);
    const int lane = t & 63;
    const int r = w >> 9, j = w & 511;
    float4 x = *(const float4*)&snb[r * 256 + lane * 4];
    float4 wv = *(const float4*)&p1w[(size_t)j * 256 + lane * 4];
    float s = wave_allreduce(dot4(x, wv));
    if (lane == 0) h1g[r * 512 + j] = fmaxf(s + p1b[j], 0.f);
    return;
  }
  const int bn = blockIdx.x % 4, bm = blockIdx.x / 4;
  const int row0 = bm * 64, col0 = bn * 128;
  const int wave = t >> 6, lane = t & 63;
  const int wm = wave >> 1, wn = wave & 1, quad = lane >> 4, mr = lane & 15;
  f32x4 acc[2][4];
#pragma unroll
  for (int mi = 0; mi < 2; mi++)
#pragma unroll
    for (int ni = 0; ni < 4; ni++) acc[mi][ni] = (f32x4){0.f, 0.f, 0.f, 0.f};
  const int arow = t >> 2, akc = t & 3;
  for (int k0 = 0; k0 < 256; k0 += 32) {
    float4 av = *(const float4*)(A + (size_t)(row0 + arow) * 256 + k0 + akc * 8);
    float4 bv0 = *(const float4*)(B + (size_t)(col0 + arow) * 256 + k0 + akc * 8);
    float4 bv1 = *(const float4*)(B + (size_t)(col0 + 64 + arow) * 256 + k0 + akc * 8);
    __syncthreads();
    *(float4*)&As[arow * 40 + akc * 8] = av;
    *(float4*)&Bs[arow * 40 + akc * 8] = bv0;
    *(float4*)&Bs[(64 + arow) * 40 + akc * 8] = bv1;
    __syncthreads();
    bf16x8 af[2], bfr[4];
#pragma unroll
    for (int mi = 0; mi < 2; mi++)
      af[mi] = *(const bf16x8*)&As[(wm * 32 + mi * 16 + mr) * 40 + quad * 8];
#pragma unroll
    for (int ni = 0; ni < 4; ni++)
      bfr[ni] = *(const bf16x8*)&Bs[(wn * 64 + ni * 16 + mr) * 40 + quad * 8];
#pragma unroll
    for (int mi = 0; mi < 2; mi++)
#pragma unroll
      for (int ni = 0; ni < 4; ni++)
        acc[mi][ni] = __builtin_amdgcn_mfma_f32_16x16x32_bf16(af[mi], bfr[ni], acc[mi][ni], 0, 0, 0);
  }
#pragma unroll
  for (int mi = 0; mi < 2; mi++) {
#pragma unroll
    for (int ni = 0; ni < 4; ni++) {
      const int col = col0 + wn * 64 + ni * 16 + mr;
      const int rb = row0 + wm * 32 + mi * 16 + quad * 4;
      const float bs = bias[col];
#pragma unroll
      for (int reg = 0; reg < 4; reg++) {
        const int row = rb + reg;
        outb[(size_t)row * 512 + col] = f2bf(fmaxf(acc[mi][ni][reg] + bs, 0.f));
      }
    }
  }
}

// ---------------- query proj2 GEMM + sup2 (verified R7) ----------------
__global__ __launch_bounds__(256) void k_proj2(
    const ushortT* __restrict__ A, const ushortT* __restrict__ B,
    const float* __restrict__ bias, const float* __restrict__ aux,
    float* __restrict__ outf,
    const float* __restrict__ snb, const float* __restrict__ h1g,
    const float* __restrict__ p2w, const float* __restrict__ p2b,
    float* __restrict__ zb) {
  __shared__ short As[64 * 40];
  __shared__ short Bs[128 * 40];
  const int t = threadIdx.x;
  if (blockIdx.x >= 128) {
    const int w = (blockIdx.x - 128) * 4 + (t >> 6);
    const int lane = t & 63;
    const int r = w >> 8, tt = w & 255;
    float4 h0 = *(const float4*)&h1g[r * 512 + lane * 4];
    float4 h1 = *(const float4*)&h1g[r * 512 + 256 + lane * 4];
    float4 w0 = *(const float4*)&p2w[(size_t)tt * 512 + lane * 4];
    float4 w1 = *(const float4*)&p2w[(size_t)tt * 512 + 256 + lane * 4];
    float s = wave_allreduce(dot4(h0, w0) + dot4(h1, w1));
    if (lane == 0) zb[r * 256 + tt] = s + p2b[tt] + snb[r * 256 + tt];
    return;
  }
  const int bn = blockIdx.x % 2, bm = blockIdx.x / 2;
  const int row0 = bm * 64, col0 = bn * 128;
  const int wave = t >> 6, lane = t & 63;
  const int wm = wave >> 1, wn = wave & 1, quad = lane >> 4, mr = lane & 15;
  f32x4 acc[2][4];
#pragma unroll
  for (int mi = 0; mi < 2; mi++)
#pragma unroll
    for (int ni = 0; ni < 4; ni++) acc[mi][ni] = (f32x4){0.f, 0.f, 0.f, 0.f};
  const int arow = t >> 2, akc = t & 3;
  for (int k0 = 0; k0 < 512; k0 += 32) {
    float4 av = *(const float4*)(A + (size_t)(row0 + arow) * 512 + k0 + akc * 8);
    float4 bv0 = *(const float4*)(B + (size_t)(col0 + arow) * 512 + k0 + akc * 8);
    float4 bv1 = *(const float4*)(B + (size_t)(col0 + 64 + arow) * 512 + k0 + akc * 8);
    __syncthreads();
    *(float4*)&As[arow * 40 + akc * 8] = av;
    *(float4*)&Bs[arow * 40 + akc * 8] = bv0;
    *(float4*)&Bs[(64 + arow) * 40 + akc * 8] = bv1;
    __syncthreads();
    bf16x8 af[2], bfr[4];
#pragma unroll
    for (int mi = 0; mi < 2; mi++)
      af[mi] = *(const bf16x8*)&As[(wm * 32 + mi * 16 + mr) * 40 + quad * 8];
#pragma unroll
    for (int ni = 0; ni < 4; ni++)
      bfr[ni] = *(const bf16x8*)&Bs[(wn * 64 + ni * 16 + mr) * 40 + quad * 8];
#pragma unroll
    for (int mi = 0; mi < 2; mi++)
#pragma unroll
      for (int ni = 0; ni < 4; ni++)
        acc[mi][ni] = __builtin_amdgcn_mfma_f32_16x16x32_bf16(af[mi], bfr[ni], acc[mi][ni], 0, 0, 0);
  }
#pragma unroll
  for (int mi = 0; mi < 2; mi++) {
#pragma unroll
    for (int ni = 0; ni < 4; ni++) {
      const int col = col0 + wn * 64 + ni * 16 + mr;
      const int rb = row0 + wm * 32 + mi * 16 + quad * 4;
      const float bs = bias[col];
#pragma unroll
      for (int reg = 0; reg < 4; reg++) {
        const int row = rb + reg;
        const size_t off = (size_t)row * 256 + col;
        outf[off] = acc[mi][ni][reg] + bs + aux[off];
      }
    }
  }
}

// ---------------- LayerNorm + sup3 (verified R7, + sgb bf16 output) ----------------
__global__ __launch_bounds__(256) void k_ln2(
    const float* __restrict__ Z, const float* __restrict__ ln_g,
    const float* __restrict__ ln_b, float* __restrict__ qg, ushortT* __restrict__ qgb,
    const float* __restrict__ zb, float* __restrict__ sg, float* __restrict__ sn_out,
    ushortT* __restrict__ sgb) {
  const int t = threadIdx.x;
  if (blockIdx.x >= BQ / 4) {
    __shared__ float rbuf[4];
    float acc = 0.f;
    for (int r = 0; r < NS; r++) {
      float z = zb[r * 256 + t];
      float s = block_allreduce(z, rbuf);
      float mu = s * (1.f / 256.f);
      float dz = z - mu;
      float s2 = block_allreduce(dz * dz, rbuf);
      float rstd = 1.f / (sqrtf(s2 * (1.f / 255.f)) + 1e-6f);
      acc += ln_g[t] * dz * rstd + ln_b[t];
      __syncthreads();
    }
    float g = acc * (1.f / (float)NS);
    sg[t] = g;
    sgb[t] = f2bf(g);
    float n2 = block_allreduce(g * g, rbuf);
    sn_out[t] = g / fmaxf(sqrtf(n2), 1e-12f);
    return;
  }
  const int row = blockIdx.x * 4 + (t >> 6);
  const int lane = t & 63;
  float4 z = *(const float4*)&Z[(size_t)row * 256 + lane * 4];
  float s = wave_allreduce(z.x + z.y + z.z + z.w);
  float mu = s * (1.f / 256.f);
  float dx = z.x - mu, dy = z.y - mu, dz = z.z - mu, dw = z.w - mu;
  float s2 = wave_allreduce(dx * dx + dy * dy + dz * dz + dw * dw);
  float rstd = 1.f / (sqrtf(s2 * (1.f / 255.f)) + 1e-6f);
  float4 g = *(const float4*)&ln_g[lane * 4];
  float4 bb = *(const float4*)&ln_b[lane * 4];
  float4 o;
  o.x = g.x * dx * rstd + bb.x;
  o.y = g.y * dy * rstd + bb.y;
  o.z = g.z * dz * rstd + bb.z;
  o.w = g.w * dw * rstd + bb.w;
  *(float4*)&qg[(size_t)row * 256 + lane * 4] = o;
  ushort4 u;
  u.x = f2bf(o.x); u.y = f2bf(o.y); u.z = f2bf(o.z); u.w = f2bf(o.w);
  *(ushort4*)&qgb[(size_t)row * 256 + lane * 4] = u;
}

// ======== LSTM strip kernel: 256 blocks x 16 rows x 1024 cols; all 4 steps + out ========
// Per block: rows [bid*16, bid*16+16). Wave w owns cols [w*256, w*256+256).
// Gate layout: col n = 4u+g (packed interleave), gate order g: 0=i,1=f,2=g,3=o.
// Phase 0: acc = qgb @ wihb^T (K=256); xw = acc + bL (kept in REGISTERS, f32).
// Phases 1-3: acc = [h | sgb] @ whh2^T (K=512); gates = acc + xw.
// Cell: lanes mr%4==0 gather f,g,o gates from lanes +1,+2,+3 via shfl, update c (LDS), h -> hS bf16.
// Only __syncthreads() — no cross-block communication anywhere.
__global__ __launch_bounds__(256) void k_lstm_strip(
    const ushortT* __restrict__ qgb, const float* __restrict__ qg,
    const ushortT* __restrict__ wihb, const ushortT* __restrict__ whh2,
    const float* __restrict__ bL, const ushortT* __restrict__ sgb,
    const float* __restrict__ sn, float* __restrict__ out) {
  __shared__ __align__(16) ushortT hS[16][264];   // h strip, bf16, k-index = unit
  __shared__ __align__(16) float qgS[16][256];    // qg strip
  __shared__ __align__(16) float cS[16][256];     // c state
  __shared__ __align__(16) float hF[16][256];     // final h (f32) for epilogue
  __shared__ __align__(16) ushortT sgS[264];      // sg bf16 (r-input)
  const int t = threadIdx.x;
  const int w = t >> 6, lane = t & 63;
  const int quad = lane >> 4, mr = lane & 15;
  const int r0 = blockIdx.x * 16;
  const int n0 = w * 256;
  // stage qg strip + sg
  for (int i = t; i < 16 * 256; i += 256) {
    int r = i >> 8, c = i & 255;
    qgS[r][c] = qg[(size_t)(r0 + r) * 256 + c];
  }
  sgS[t] = sgb[t];
  __syncthreads();
  // per-lane per-col-tile bias (bias depends on col only)
  float bLs[16];
#pragma unroll
  for (int ct = 0; ct < 16; ct++) bLs[ct] = bL[n0 + ct * 16 + mr];

  f32x4 accv[16];
  f32x4 xwv[16];
  const int base = lane & ~3;

#pragma unroll
  for (int p = 0; p < 4; p++) {
    const int K = (p == 0) ? 256 : 512;
    const ushortT* Bp = (p == 0) ? wihb : whh2;
#pragma unroll
    for (int ct = 0; ct < 16; ct++) accv[ct] = (f32x4){0.f, 0.f, 0.f, 0.f};
    for (int k0 = 0; k0 < K; k0 += 32) {
      bf16x8 af;
      if (p == 0)
        af = *(const bf16x8*)&qgb[(size_t)(r0 + mr) * 256 + k0 + quad * 8];
      else if (k0 < 256)
        af = *(const bf16x8*)&hS[mr][k0 + quad * 8];
      else
        af = *(const bf16x8*)&sgS[(k0 - 256) + quad * 8];
#pragma unroll
      for (int ct = 0; ct < 16; ct++) {
        bf16x8 bf = *(const bf16x8*)&Bp[(size_t)(n0 + ct * 16 + mr) * K + k0 + quad * 8];
        accv[ct] = __builtin_amdgcn_mfma_f32_16x16x32_bf16(af, bf, accv[ct], 0, 0, 0);
      }
    }
    __syncthreads();  // all reads of hS complete before this phase's writes
#pragma unroll
    for (int ct = 0; ct < 16; ct++) {
      if (p == 0) {
        accv[ct][0] += bLs[ct]; accv[ct][1] += bLs[ct];
        accv[ct][2] += bLs[ct]; accv[ct][3] += bLs[ct];
        xwv[ct] = accv[ct];
      } else {
        accv[ct][0] += xwv[ct][0]; accv[ct][1] += xwv[ct][1];
        accv[ct][2] += xwv[ct][2]; accv[ct][3] += xwv[ct][3];
      }
      // gather the 4 gates of each unit onto the leader lane (mr%4==0)
      f32x4 gi = accv[ct];
      f32x4 gf, gg, go;
#pragma unroll
      for (int c = 0; c < 4; c++) {
        gf[c] = __shfl(gi[c], base + 1, 64);
        gg[c] = __shfl(gi[c], base + 2, 64);
        go[c] = __shfl(gi[c], base + 3, 64);
      }
      if ((lane & 3) == 0) {
        const int u = (n0 + ct * 16 + mr) >> 2;  // unit index 0..255
#pragma unroll
        for (int reg = 0; reg < 4; reg++) {
          const int r = quad * 4 + reg;
          float c_;
          if (p == 0) c_ = sigm(gi[reg]) * tanhf(gg[reg]);
          else        c_ = sigm(gf[reg]) * cS[r][u] + sigm(gi[reg]) * tanhf(gg[reg]);
          float h = qgS[r][u] + sigm(go[reg]) * tanhf(c_);
          cS[r][u] = c_;
          if (p < 3) hS[r][u] = f2bf(h);
          else       hF[r][u] = h;
        }
      }
    }
    __syncthreads();  // h writes visible to all waves before next phase
  }
  // ---- output epilogue: out[row] = (h.sn) / ||h|| ----
  float4 snv = *(const float4*)&sn[lane * 4];
#pragma unroll
  for (int rr = 0; rr < 4; rr++) {
    const int r = w * 4 + rr;
    float4 h = *(const float4*)&hF[r][lane * 4];
    float dt = wave_allreduce(dot4(h, snv));
    float nr = wave_allreduce(dot4(h, h));
    if (lane == 0) out[r0 + r] = dt / fmaxf(sqrtf(nr), 1e-12f);
  }
}

extern "C" void kernel_launch(void* const* d_in, const int* in_sizes, int n_in,
                              void* d_out, int out_size, void* d_ws, size_t ws_size,
                              hipStream_t stream) {
  const int* q_l_conn = (const int*)d_in[2];
  const int* q_l_deg  = (const int*)d_in[3];
  const int* q_r_conn = (const int*)d_in[4];
  const int* q_r_deg  = (const int*)d_in[5];
  const int* s_l_conn = (const int*)d_in[6];
  const int* s_l_deg  = (const int*)d_in[7];
  const int* s_r_conn = (const int*)d_in[8];
  const int* s_r_deg  = (const int*)d_in[9];
  const float* emb      = (const float*)d_in[10];
  const float* gcn_w    = (const float*)d_in[11];
  const float* gcn_bias = (const float*)d_in[12];
  const float* proj1_w  = (const float*)d_in[13];
  const float* proj1_b  = (const float*)d_in[14];
  const float* proj2_w  = (const float*)d_in[15];
  const float* proj2_b  = (const float*)d_in[16];
  const float* ln_g     = (const float*)d_in[17];
  const float* ln_b     = (const float*)d_in[18];
  const float* w_ih     = (const float*)d_in[19];
  const float* w_hh     = (const float*)d_in[20];
  const float* b_ih     = (const float*)d_in[21];
  const float* b_hh     = (const float*)d_in[22];

  float* ws = (float*)d_ws;
  float* qnb   = ws + WS_QNB;
  float* Z     = ws + WS_Z;
  float* qg    = ws + WS_QG;
  ushortT* whh2  = (ushortT*)(ws + WS_WHH2);
  ushortT* XS    = (ushortT*)(ws + WS_XS);
  ushortT* h1b   = (ushortT*)(ws + WS_H1B);
  ushortT* abf   = (ushortT*)(ws + WS_ABF);
  ushortT* p1b16 = (ushortT*)(ws + WS_P1B);
  ushortT* p2b16 = (ushortT*)(ws + WS_P2B);
  ushortT* wihb  = (ushortT*)(ws + WS_WIHB);
  ushortT* gwb   = (ushortT*)(ws + WS_GWB);
  float* snb   = ws + WS_SNB;
  float* h1g   = ws + WS_H1G;
  float* zb    = ws + WS_ZB;
  float* sg    = ws + WS_SG;
  float* sn    = ws + WS_SN;
  ushortT* sgb = (ushortT*)(ws + WS_SGB);
  float* bL    = ws + WS_BL;
  ushortT* emb16 = (ushortT*)(ws + WS_EMB16);
  float* out   = (float*)d_out;

  const size_t needF = (size_t)WS_EMB16 + (EMB_ELEMS + 1) / 2;
  const int useBf16 = (ws_size >= needF * sizeof(float)) ? 1 : 0;

  hipLaunchKernelGGL(k_prep, dim3(2048), dim3(256), 0, stream,
                     emb, emb16, useBf16,
                     w_ih, w_hh, proj1_w, proj2_w, gcn_w, b_ih, b_hh,
                     p1b16, p2b16, wihb, whh2, gwb, bL);
  if (useBf16) {
    hipLaunchKernelGGL(k_gather16, dim3(2 * (BQ + NS)), dim3(256), 0, stream,
                       q_l_conn, q_r_conn, s_l_conn, s_r_conn, emb16, XS);
  } else {
    hipLaunchKernelGGL(k_gather32, dim3(2 * (BQ + NS)), dim3(256), 0, stream,
                       q_l_conn, q_r_conn, s_l_conn, s_r_conn, emb, XS);
  }
  hipLaunchKernelGGL(k_gcn, dim3(129), dim3(256), 0, stream,
                     XS, gwb, gcn_bias, q_l_deg, q_r_deg, s_l_deg, s_r_deg,
                     qnb, snb, abf);
  hipLaunchKernelGGL(k_proj1, dim3(256 + 640), dim3(256), 0, stream,
                     abf, p1b16, proj1_b, h1b,
                     snb, proj1_w, proj1_b, h1g);
  hipLaunchKernelGGL(k_proj2, dim3(128 + 320), dim3(256), 0, stream,
                     h1b, p2b16, proj2_b, qnb, Z,
                     snb, h1g, proj2_w, proj2_b, zb);
  hipLaunchKernelGGL(k_ln2, dim3(BQ / 4 + 1), dim3(256), 0, stream,
                     Z, ln_g, ln_b, qg, abf, zb, sg, sn, sgb);
  hipLaunchKernelGGL(k_lstm_strip, dim3(256), dim3(256), 0, stream,
                     abf, qg, wihb, whh2, bL, sgb, sn, out);
}

// Round 12
// 330.108 us; speedup vs baseline: 1.6272x; 1.6272x over previous
//
#include <hip/hip_runtime.h>

#define BQ 4096
#define NS 5

typedef __attribute__((ext_vector_type(8))) short bf16x8;
typedef __attribute__((ext_vector_type(4))) float f32x4;
typedef unsigned short ushortT;

// ---------------- ws layout (float offsets) ----------------
#define WS_QNB    0          // 4096*256 f32
#define WS_Z      1048576    // 4096*256 f32
#define WS_QG     2097152    // 4096*256 f32
#define WS_XW     3145728    // 4096*1024 bf16 = 2097152 f32-units
#define WS_CBUF   5242880    // 4096*256 f32
#define WS_XS     6291456    // 8256*256 bf16 = 1056768 f32-units
#define WS_H1B    7348224    // 4096*512 bf16 = 524288
#define WS_ABF    7872512    // 4096*256 bf16 = 262144 (Xq / Qgb / h dbuf B)
#define WS_HB1    8134656    // 4096*256 bf16 (h dbuf A)
#define WS_P1B    8396800    // 512*256 bf16 = 65536
#define WS_P2B    8462336    // 256*512 bf16
#define WS_WIHB   8527872    // 1024*256 bf16 = 131072
#define WS_WHHB   8658944    // 1024*256 bf16
#define WS_GWB    8790016    // 128*256 bf16 = 16384
#define WS_SNB    8806400    // 5*256
#define WS_H1G    8807680    // 5*512
#define WS_ZB     8810240    // 5*256
#define WS_SG     8811520    // 256
#define WS_SN     8811776    // 256
#define WS_SWL    8812032    // 1024 (interleaved n=4u+g)
#define WS_BL     8813056    // 1024
#define WS_EMB16  8814080    // 200001*128 bf16 = 12800064 f32-units (optional)
#define EMB_ELEMS 25600128   // 200001*128

__device__ __forceinline__ float wave_allreduce(float v) {
#pragma unroll
  for (int off = 32; off > 0; off >>= 1) v += __shfl_xor(v, off, 64);
  return v;
}
__device__ __forceinline__ float block_allreduce(float v, float* buf) {
  v = wave_allreduce(v);
  __syncthreads();
  if ((threadIdx.x & 63) == 0) buf[threadIdx.x >> 6] = v;
  __syncthreads();
  return buf[0] + buf[1] + buf[2] + buf[3];
}
__device__ __forceinline__ float sigm(float x) { return 1.0f / (1.0f + expf(-x)); }
__device__ __forceinline__ ushortT f2bf(float f) {
  unsigned int u = __float_as_uint(f);
  unsigned int r = (u + 0x7fffu + ((u >> 16) & 1u)) >> 16;
  return (ushortT)r;
}
__device__ __forceinline__ float bf2f(ushortT u) {
  return __uint_as_float(((unsigned int)u) << 16);
}
__device__ __forceinline__ float dot4(float4 a, float4 b) {
  return a.x * b.x + a.y * b.y + a.z * b.z + a.w * b.w;
}

// ---------------- prep: emb fp32 -> bf16 (optional) + weight pack ----------------
__global__ __launch_bounds__(256) void k_prep(
    const float* __restrict__ emb, ushortT* __restrict__ emb16, int doEmb,
    const float* __restrict__ w_ih, const float* __restrict__ w_hh,
    const float* __restrict__ p1w, const float* __restrict__ p2w,
    const float* __restrict__ gcn_w,
    const float* __restrict__ b_ih, const float* __restrict__ b_hh,
    ushortT* __restrict__ p1b16, ushortT* __restrict__ p2b16,
    ushortT* __restrict__ wihb, ushortT* __restrict__ whhb,
    ushortT* __restrict__ gwb, float* __restrict__ bL) {
  const int gid = blockIdx.x * 256 + threadIdx.x;
  const int stride = gridDim.x * 256;
  if (doEmb) {
    const float4* e4 = (const float4*)emb;
    ushort4* o4 = (ushort4*)emb16;
    for (int i = gid; i < EMB_ELEMS / 4; i += stride) {
      float4 v = e4[i];
      ushort4 u;
      u.x = f2bf(v.x); u.y = f2bf(v.y); u.z = f2bf(v.z); u.w = f2bf(v.w);
      o4[i] = u;
    }
  }
  for (int i = gid; i < 131072; i += stride) p1b16[i] = f2bf(p1w[i]);
  for (int i = gid; i < 131072; i += stride) p2b16[i] = f2bf(p2w[i]);
  for (int i = gid; i < 262144; i += stride) {
    int n = i >> 8, k = i & 255;
    int j = (n >> 2) + 512 * (n & 3);
    wihb[i] = f2bf(w_ih[j * 256 + k]);
    whhb[i] = f2bf(w_hh[j * 512 + k]);
  }
  for (int i = gid; i < 32768; i += stride) gwb[i] = f2bf(gcn_w[i]);
  for (int i = gid; i < 1024; i += stride) {
    int j = (i >> 2) + 512 * (i & 3);
    bL[i] = b_ih[j] + b_hh[j];
  }
}

// ---------------- gather+sum from bf16 table: 16 row-loads in flight ----------------
__global__ __launch_bounds__(256) void k_gather16(
    const int* __restrict__ qlc, const int* __restrict__ qrc,
    const int* __restrict__ slc, const int* __restrict__ src_,
    const ushortT* __restrict__ emb16, ushortT* __restrict__ XS) {
  const int r = blockIdx.x;
  const int b = r >> 1, side = r & 1;
  const int t = threadIdx.x;
  const int* cg2;
  if (b < BQ) cg2 = (side ? qrc : qlc) + (size_t)b * 128;
  else        cg2 = (side ? src_ : slc) + (size_t)(b - BQ) * 128;
  __shared__ int connS[128];
  __shared__ __align__(16) float part[8][132];
  if (t < 128) connS[t] = cg2[t];
  __syncthreads();
  const int s = t >> 5, l = t & 31;
  const ushort4* e2 = (const ushort4*)emb16;
  float4 acc = make_float4(0.f, 0.f, 0.f, 0.f);
  int im[16];
#pragma unroll
  for (int k = 0; k < 16; k++) im[k] = connS[k * 8 + s];
  ushort4 v[16];
#pragma unroll
  for (int k = 0; k < 16; k++) v[k] = e2[(size_t)im[k] * 32 + l];
#pragma unroll
  for (int k = 0; k < 16; k++) {
    acc.x += bf2f(v[k].x); acc.y += bf2f(v[k].y);
    acc.z += bf2f(v[k].z); acc.w += bf2f(v[k].w);
  }
  *(float4*)&part[s][l * 4] = acc;
  __syncthreads();
  const int hf = t >> 7, dd = t & 127;
  float sum = part[hf][dd] + part[2 + hf][dd] + part[4 + hf][dd] + part[6 + hf][dd];
  XS[(size_t)r * 256 + t] = f2bf(sum);
}

// ---------------- fallback gather from fp32 table (verified path) ----------------
__global__ __launch_bounds__(256) void k_gather32(
    const int* __restrict__ qlc, const int* __restrict__ qrc,
    const int* __restrict__ slc, const int* __restrict__ src_,
    const float* __restrict__ emb, ushortT* __restrict__ XS) {
  const int r = blockIdx.x;
  const int b = r >> 1, side = r & 1;
  const int t = threadIdx.x;
  const int* cg2;
  if (b < BQ) cg2 = (side ? qrc : qlc) + (size_t)b * 128;
  else        cg2 = (side ? src_ : slc) + (size_t)(b - BQ) * 128;
  __shared__ int connS[128];
  __shared__ __align__(16) float part[8][132];
  if (t < 128) connS[t] = cg2[t];
  __syncthreads();
  const int s = t >> 5, l = t & 31;
  const float4* emb4 = (const float4*)emb;
  float4 acc = make_float4(0.f, 0.f, 0.f, 0.f);
#pragma unroll
  for (int kb = 0; kb < 2; kb++) {
    int im[8];
#pragma unroll
    for (int k = 0; k < 8; k++) im[k] = connS[(kb * 8 + k) * 8 + s];
    float4 v[8];
#pragma unroll
    for (int k = 0; k < 8; k++) v[k] = emb4[(size_t)im[k] * 32 + l];
#pragma unroll
    for (int k = 0; k < 8; k++) {
      acc.x += v[k].x; acc.y += v[k].y; acc.z += v[k].z; acc.w += v[k].w;
    }
  }
  *(float4*)&part[s][l * 4] = acc;
  __syncthreads();
  const int hf = t >> 7, dd = t & 127;
  float sum = part[hf][dd] + part[2 + hf][dd] + part[4 + hf][dd] + part[6 + hf][dd];
  XS[(size_t)r * 256 + t] = f2bf(sum);
}

// ---------------- GCN matvec as MFMA GEMM + tanh/deg epilogue ----------------
__global__ __launch_bounds__(256) void k_gcn(
    const ushortT* __restrict__ XS, const ushortT* __restrict__ gwb,
    const float* __restrict__ gcn_bias,
    const int* __restrict__ qld, const int* __restrict__ qrd,
    const int* __restrict__ sld, const int* __restrict__ srd,
    float* __restrict__ qnb, float* __restrict__ snb, ushortT* __restrict__ xq) {
  __shared__ short As[64 * 40];
  __shared__ short Bs[128 * 40];
  __shared__ int degl[32], degr[32];
  const int t = threadIdx.x;
  const int row0 = blockIdx.x * 64;
  if (t < 32) {
    int b = (row0 >> 1) + t;
    int dl = 1, dr = 1;
    if (b < BQ) { dl = qld[b]; dr = qrd[b]; }
    else if (b < BQ + NS) { dl = sld[b - BQ]; dr = srd[b - BQ]; }
    degl[t] = (dl > 0) ? dl : 1;
    degr[t] = (dr > 0) ? dr : 1;
  }
  const int wave = t >> 6, lane = t & 63;
  const int wm = wave >> 1, wn = wave & 1, quad = lane >> 4, mr = lane & 15;
  f32x4 acc[2][4];
#pragma unroll
  for (int mi = 0; mi < 2; mi++)
#pragma unroll
    for (int ni = 0; ni < 4; ni++) acc[mi][ni] = (f32x4){0.f, 0.f, 0.f, 0.f};
  const int arow = t >> 2, akc = t & 3;
  for (int k0 = 0; k0 < 256; k0 += 32) {
    float4 av = *(const float4*)(XS + (size_t)(row0 + arow) * 256 + k0 + akc * 8);
    float4 bv0 = *(const float4*)(gwb + (size_t)arow * 256 + k0 + akc * 8);
    float4 bv1 = *(const float4*)(gwb + (size_t)(64 + arow) * 256 + k0 + akc * 8);
    __syncthreads();
    *(float4*)&As[arow * 40 + akc * 8] = av;
    *(float4*)&Bs[arow * 40 + akc * 8] = bv0;
    *(float4*)&Bs[(64 + arow) * 40 + akc * 8] = bv1;
    __syncthreads();
    bf16x8 af[2], bfr[4];
#pragma unroll
    for (int mi = 0; mi < 2; mi++)
      af[mi] = *(const bf16x8*)&As[(wm * 32 + mi * 16 + mr) * 40 + quad * 8];
#pragma unroll
    for (int ni = 0; ni < 4; ni++)
      bfr[ni] = *(const bf16x8*)&Bs[(wn * 64 + ni * 16 + mr) * 40 + quad * 8];
#pragma unroll
    for (int mi = 0; mi < 2; mi++)
#pragma unroll
      for (int ni = 0; ni < 4; ni++)
        acc[mi][ni] = __builtin_amdgcn_mfma_f32_16x16x32_bf16(af[mi], bfr[ni], acc[mi][ni], 0, 0, 0);
  }
#pragma unroll
  for (int mi = 0; mi < 2; mi++) {
#pragma unroll
    for (int ni = 0; ni < 4; ni++) {
      const int col = wn * 64 + ni * 16 + mr;
      const int rb = row0 + wm * 32 + mi * 16 + quad * 4;
      const float bs = 64.0f * gcn_bias[col];
#pragma unroll
      for (int reg = 0; reg < 4; reg++) {
        const int row = rb + reg;
        const int b = row >> 1, side = row & 1;
        if (b >= BQ + NS) continue;
        const int li = (row >> 1) - (row0 >> 1);
        const int deg = side ? degr[li] : degl[li];
        float val = tanhf((acc[mi][ni][reg] + bs) / (float)deg);
        if (b < BQ) {
          const size_t o = (size_t)b * 256 + side * 128 + col;
          qnb[o] = val;
          xq[o] = f2bf(val);
        } else {
          snb[(size_t)(b - BQ) * 256 + side * 128 + col] = val;
        }
      }
    }
  }
}

// ---------------- query proj1 GEMM (blocks 0..255) + sup1 wave-dots (blocks 256..895) ----------------
__global__ __launch_bounds__(256) void k_proj1(
    const ushortT* __restrict__ A, const ushortT* __restrict__ B,
    const float* __restrict__ bias, ushortT* __restrict__ outb,
    const float* __restrict__ snb, const float* __restrict__ p1w,
    const float* __restrict__ p1b, float* __restrict__ h1g) {
  __shared__ short As[64 * 40];
  __shared__ short Bs[128 * 40];
  const int t = threadIdx.x;
  if (blockIdx.x >= 256) {
    // ---- sup1: h1g[r][j] = relu(snb[r,:] . p1w[j,:] + p1b[j]) ----
    const int w = (blockIdx.x - 256) * 4 + (t >> 6);
    const int lane = t & 63;
    const int r = w >> 9, j = w & 511;
    float4 x = *(const float4*)&snb[r * 256 + lane * 4];
    float4 wv = *(const float4*)&p1w[(size_t)j * 256 + lane * 4];
    float s = wave_allreduce(dot4(x, wv));
    if (lane == 0) h1g[r * 512 + j] = fmaxf(s + p1b[j], 0.f);
    return;
  }
  const int bn = blockIdx.x % 4, bm = blockIdx.x / 4;
  const int row0 = bm * 64, col0 = bn * 128;
  const int wave = t >> 6, lane = t & 63;
  const int wm = wave >> 1, wn = wave & 1, quad = lane >> 4, mr = lane & 15;
  f32x4 acc[2][4];
#pragma unroll
  for (int mi = 0; mi < 2; mi++)
#pragma unroll
    for (int ni = 0; ni < 4; ni++) acc[mi][ni] = (f32x4){0.f, 0.f, 0.f, 0.f};
  const int arow = t >> 2, akc = t & 3;
  for (int k0 = 0; k0 < 256; k0 += 32) {
    float4 av = *(const float4*)(A + (size_t)(row0 + arow) * 256 + k0 + akc * 8);
    float4 bv0 = *(const float4*)(B + (size_t)(col0 + arow) * 256 + k0 + akc * 8);
    float4 bv1 = *(const float4*)(B + (size_t)(col0 + 64 + arow) * 256 + k0 + akc * 8);
    __syncthreads();
    *(float4*)&As[arow * 40 + akc * 8] = av;
    *(float4*)&Bs[arow * 40 + akc * 8] = bv0;
    *(float4*)&Bs[(64 + arow) * 40 + akc * 8] = bv1;
    __syncthreads();
    bf16x8 af[2], bfr[4];
#pragma unroll
    for (int mi = 0; mi < 2; mi++)
      af[mi] = *(const bf16x8*)&As[(wm * 32 + mi * 16 + mr) * 40 + quad * 8];
#pragma unroll
    for (int ni = 0; ni < 4; ni++)
      bfr[ni] = *(const bf16x8*)&Bs[(wn * 64 + ni * 16 + mr) * 40 + quad * 8];
#pragma unroll
    for (int mi = 0; mi < 2; mi++)
#pragma unroll
      for (int ni = 0; ni < 4; ni++)
        acc[mi][ni] = __builtin_amdgcn_mfma_f32_16x16x32_bf16(af[mi], bfr[ni], acc[mi][ni], 0, 0, 0);
  }
#pragma unroll
  for (int mi = 0; mi < 2; mi++) {
#pragma unroll
    for (int ni = 0; ni < 4; ni++) {
      const int col = col0 + wn * 64 + ni * 16 + mr;
      const int rb = row0 + wm * 32 + mi * 16 + quad * 4;
      const float bs = bias[col];
#pragma unroll
      for (int reg = 0; reg < 4; reg++) {
        const int row = rb + reg;
        outb[(size_t)row * 512 + col] = f2bf(fmaxf(acc[mi][ni][reg] + bs, 0.f));
      }
    }
  }
}

// ---------------- query proj2 GEMM mode1 (blocks 0..127) + sup2 (blocks 128..447) ----------------
__global__ __launch_bounds__(256) void k_proj2(
    const ushortT* __restrict__ A, const ushortT* __restrict__ B,
    const float* __restrict__ bias, const float* __restrict__ aux,
    float* __restrict__ outf,
    const float* __restrict__ snb, const float* __restrict__ h1g,
    const float* __restrict__ p2w, const float* __restrict__ p2b,
    float* __restrict__ zb) {
  __shared__ short As[64 * 40];
  __shared__ short Bs[128 * 40];
  const int t = threadIdx.x;
  if (blockIdx.x >= 128) {
    // ---- sup2: zb[r][tt] = h1g[r,:] . p2w[tt,:] + p2b[tt] + snb[r][tt] ----
    const int w = (blockIdx.x - 128) * 4 + (t >> 6);
    const int lane = t & 63;
    const int r = w >> 8, tt = w & 255;
    float4 h0 = *(const float4*)&h1g[r * 512 + lane * 4];
    float4 h1 = *(const float4*)&h1g[r * 512 + 256 + lane * 4];
    float4 w0 = *(const float4*)&p2w[(size_t)tt * 512 + lane * 4];
    float4 w1 = *(const float4*)&p2w[(size_t)tt * 512 + 256 + lane * 4];
    float s = wave_allreduce(dot4(h0, w0) + dot4(h1, w1));
    if (lane == 0) zb[r * 256 + tt] = s + p2b[tt] + snb[r * 256 + tt];
    return;
  }
  const int bn = blockIdx.x % 2, bm = blockIdx.x / 2;
  const int row0 = bm * 64, col0 = bn * 128;
  const int wave = t >> 6, lane = t & 63;
  const int wm = wave >> 1, wn = wave & 1, quad = lane >> 4, mr = lane & 15;
  f32x4 acc[2][4];
#pragma unroll
  for (int mi = 0; mi < 2; mi++)
#pragma unroll
    for (int ni = 0; ni < 4; ni++) acc[mi][ni] = (f32x4){0.f, 0.f, 0.f, 0.f};
  const int arow = t >> 2, akc = t & 3;
  for (int k0 = 0; k0 < 512; k0 += 32) {
    float4 av = *(const float4*)(A + (size_t)(row0 + arow) * 512 + k0 + akc * 8);
    float4 bv0 = *(const float4*)(B + (size_t)(col0 + arow) * 512 + k0 + akc * 8);
    float4 bv1 = *(const float4*)(B + (size_t)(col0 + 64 + arow) * 512 + k0 + akc * 8);
    __syncthreads();
    *(float4*)&As[arow * 40 + akc * 8] = av;
    *(float4*)&Bs[arow * 40 + akc * 8] = bv0;
    *(float4*)&Bs[(64 + arow) * 40 + akc * 8] = bv1;
    __syncthreads();
    bf16x8 af[2], bfr[4];
#pragma unroll
    for (int mi = 0; mi < 2; mi++)
      af[mi] = *(const bf16x8*)&As[(wm * 32 + mi * 16 + mr) * 40 + quad * 8];
#pragma unroll
    for (int ni = 0; ni < 4; ni++)
      bfr[ni] = *(const bf16x8*)&Bs[(wn * 64 + ni * 16 + mr) * 40 + quad * 8];
#pragma unroll
    for (int mi = 0; mi < 2; mi++)
#pragma unroll
      for (int ni = 0; ni < 4; ni++)
        acc[mi][ni] = __builtin_amdgcn_mfma_f32_16x16x32_bf16(af[mi], bfr[ni], acc[mi][ni], 0, 0, 0);
  }
#pragma unroll
  for (int mi = 0; mi < 2; mi++) {
#pragma unroll
    for (int ni = 0; ni < 4; ni++) {
      const int col = col0 + wn * 64 + ni * 16 + mr;
      const int rb = row0 + wm * 32 + mi * 16 + quad * 4;
      const float bs = bias[col];
#pragma unroll
      for (int reg = 0; reg < 4; reg++) {
        const int row = rb + reg;
        const size_t off = (size_t)row * 256 + col;
        outf[off] = acc[mi][ni][reg] + bs + aux[off];
      }
    }
  }
}

// ---------------- LayerNorm rows of Z (blocks 0..1023) + sup3 (block 1024) ----------------
__global__ __launch_bounds__(256) void k_ln2(
    const float* __restrict__ Z, const float* __restrict__ ln_g,
    const float* __restrict__ ln_b, float* __restrict__ qg, ushortT* __restrict__ qgb,
    const float* __restrict__ zb, float* __restrict__ sg, float* __restrict__ sn_out) {
  const int t = threadIdx.x;
  if (blockIdx.x >= BQ / 4) {
    // ---- sup3: mean of per-row LN over 5 support rows -> sg; normalized -> sn ----
    __shared__ float rbuf[4];
    float acc = 0.f;
    for (int r = 0; r < NS; r++) {
      float z = zb[r * 256 + t];
      float s = block_allreduce(z, rbuf);
      float mu = s * (1.f / 256.f);
      float dz = z - mu;
      float s2 = block_allreduce(dz * dz, rbuf);
      float rstd = 1.f / (sqrtf(s2 * (1.f / 255.f)) + 1e-6f);
      acc += ln_g[t] * dz * rstd + ln_b[t];
      __syncthreads();
    }
    float g = acc * (1.f / (float)NS);
    sg[t] = g;
    float n2 = block_allreduce(g * g, rbuf);
    sn_out[t] = g / fmaxf(sqrtf(n2), 1e-12f);
    return;
  }
  const int row = blockIdx.x * 4 + (t >> 6);
  const int lane = t & 63;
  float4 z = *(const float4*)&Z[(size_t)row * 256 + lane * 4];
  float s = wave_allreduce(z.x + z.y + z.z + z.w);
  float mu = s * (1.f / 256.f);
  float dx = z.x - mu, dy = z.y - mu, dz = z.z - mu, dw = z.w - mu;
  float s2 = wave_allreduce(dx * dx + dy * dy + dz * dz + dw * dw);
  float rstd = 1.f / (sqrtf(s2 * (1.f / 255.f)) + 1e-6f);
  float4 g = *(const float4*)&ln_g[lane * 4];
  float4 bb = *(const float4*)&ln_b[lane * 4];
  float4 o;
  o.x = g.x * dx * rstd + bb.x;
  o.y = g.y * dy * rstd + bb.y;
  o.z = g.z * dz * rstd + bb.z;
  o.w = g.w * dw * rstd + bb.w;
  *(float4*)&qg[(size_t)row * 256 + lane * 4] = o;
  ushort4 u;
  u.x = f2bf(o.x); u.y = f2bf(o.y); u.z = f2bf(o.z); u.w = f2bf(o.w);
  *(ushort4*)&qgb[(size_t)row * 256 + lane * 4] = u;
}

// ---------------- LSTM GEMM with fused gate epilogue (xw in bf16) ----------------
// phase 0: xwb stores xW+b only (NO sWl); sup4 rides as blocks 512..767 computing sWl.
// phases 1..3: gates = bf2f(xwb) + sWl + h@whhb^T.
__global__ __launch_bounds__(256) void k_gemm_lstm(
    const ushortT* __restrict__ A, const ushortT* __restrict__ B,
    const float* __restrict__ bL, float* __restrict__ sWl,
    const float* __restrict__ qg, ushortT* __restrict__ xwb,
    float* __restrict__ cbuf, ushortT* __restrict__ hb_out,
    const float* __restrict__ sg, const float* __restrict__ w_hh, int phase) {
  __shared__ short As[64 * 40];
  __shared__ short Bs[128 * 40];
  __shared__ __align__(16) float Cs[64 * 132];
  const int t = threadIdx.x;
  if (blockIdx.x >= 512) {
    // ---- sup4 (phase-0 launch only): sWl[n] = sg . w_hh[j, 256:512] ----
    const int n = (blockIdx.x - 512) * 4 + (t >> 6);
    const int lane = t & 63;
    const int j = (n >> 2) + 512 * (n & 3);
    float4 x = *(const float4*)&sg[lane * 4];
    float4 wv = *(const float4*)&w_hh[(size_t)j * 512 + 256 + lane * 4];
    float s = wave_allreduce(dot4(x, wv));
    if (lane == 0) sWl[n] = s;
    return;
  }
  const int bn = blockIdx.x & 7, bm = blockIdx.x >> 3;
  const int row0 = bm * 64, col0 = bn * 128;
  const int wave = t >> 6, lane = t & 63;
  const int wm = wave >> 1, wn = wave & 1, quad = lane >> 4, mr = lane & 15;
  f32x4 acc[2][4];
#pragma unroll
  for (int mi = 0; mi < 2; mi++)
#pragma unroll
    for (int ni = 0; ni < 4; ni++) acc[mi][ni] = (f32x4){0.f, 0.f, 0.f, 0.f};
  const int arow = t >> 2, akc = t & 3;
  for (int k0 = 0; k0 < 256; k0 += 32) {
    float4 av = *(const float4*)(A + (size_t)(row0 + arow) * 256 + k0 + akc * 8);
    float4 bv0 = *(const float4*)(B + (size_t)(col0 + arow) * 256 + k0 + akc * 8);
    float4 bv1 = *(const float4*)(B + (size_t)(col0 + 64 + arow) * 256 + k0 + akc * 8);
    __syncthreads();
    *(float4*)&As[arow * 40 + akc * 8] = av;
    *(float4*)&Bs[arow * 40 + akc * 8] = bv0;
    *(float4*)&Bs[(64 + arow) * 40 + akc * 8] = bv1;
    __syncthreads();
    bf16x8 af[2], bfr[4];
#pragma unroll
    for (int mi = 0; mi < 2; mi++)
      af[mi] = *(const bf16x8*)&As[(wm * 32 + mi * 16 + mr) * 40 + quad * 8];
#pragma unroll
    for (int ni = 0; ni < 4; ni++)
      bfr[ni] = *(const bf16x8*)&Bs[(wn * 64 + ni * 16 + mr) * 40 + quad * 8];
#pragma unroll
    for (int mi = 0; mi < 2; mi++)
#pragma unroll
      for (int ni = 0; ni < 4; ni++)
        acc[mi][ni] = __builtin_amdgcn_mfma_f32_16x16x32_bf16(af[mi], bfr[ni], acc[mi][ni], 0, 0, 0);
  }
#pragma unroll
  for (int mi = 0; mi < 2; mi++)
#pragma unroll
    for (int ni = 0; ni < 4; ni++)
#pragma unroll
      for (int reg = 0; reg < 4; reg++)
        Cs[(wm * 32 + mi * 16 + quad * 4 + reg) * 132 + wn * 64 + ni * 16 + mr] =
            acc[mi][ni][reg];
  __syncthreads();
  const int u = t & 31, grp = t >> 5;
  const int ugl = bn * 32 + u;
#pragma unroll
  for (int i = 0; i < 8; i++) {
    const int rl = grp * 8 + i;
    const int row = row0 + rl;
    const size_t o = (size_t)row * 256 + ugl;
    float4 gv = *(const float4*)&Cs[rl * 132 + u * 4];
    if (phase == 0) {
      float4 bb = *(const float4*)&bL[col0 + u * 4];
      gv.x += bb.x; gv.y += bb.y; gv.z += bb.z; gv.w += bb.w;
      float c0 = sigm(gv.x) * tanhf(gv.z);
      float h = qg[o] + sigm(gv.w) * tanhf(c0);
      cbuf[o] = c0;
      hb_out[o] = f2bf(h);
      ushort4 xo;
      xo.x = f2bf(gv.x); xo.y = f2bf(gv.y);
      xo.z = f2bf(gv.z); xo.w = f2bf(gv.w);
      *(ushort4*)&xwb[(size_t)row * 1024 + col0 + u * 4] = xo;
    } else {
      ushort4 xv = *(const ushort4*)&xwb[(size_t)row * 1024 + col0 + u * 4];
      float4 sv = *(const float4*)&sWl[col0 + u * 4];
      gv.x += bf2f(xv.x) + sv.x; gv.y += bf2f(xv.y) + sv.y;
      gv.z += bf2f(xv.z) + sv.z; gv.w += bf2f(xv.w) + sv.w;
      float c = sigm(gv.y) * cbuf[o] + sigm(gv.x) * tanhf(gv.z);
      float h = qg[o] + sigm(gv.w) * tanhf(c);
      if (phase == 2) {
        cbuf[o] = h;
      } else {
        cbuf[o] = c;
        hb_out[o] = f2bf(h);
      }
    }
  }
}

// ---------------- epilogue ----------------
__global__ __launch_bounds__(256) void k_out(
    const float* __restrict__ hf, const float* __restrict__ sn, float* __restrict__ out) {
  const int t = threadIdx.x;
  const int row = blockIdx.x * 4 + (t >> 6);
  const int lane = t & 63;
  float4 h = *(const float4*)&hf[(size_t)row * 256 + lane * 4];
  float4 s = *(const float4*)&sn[lane * 4];
  float dt = wave_allreduce(dot4(h, s));
  float nr = wave_allreduce(dot4(h, h));
  if (lane == 0) out[row] = dt / fmaxf(sqrtf(nr), 1e-12f);
}

extern "C" void kernel_launch(void* const* d_in, const int* in_sizes, int n_in,
                              void* d_out, int out_size, void* d_ws, size_t ws_size,
                              hipStream_t stream) {
  const int* q_l_conn = (const int*)d_in[2];
  const int* q_l_deg  = (const int*)d_in[3];
  const int* q_r_conn = (const int*)d_in[4];
  const int* q_r_deg  = (const int*)d_in[5];
  const int* s_l_conn = (const int*)d_in[6];
  const int* s_l_deg  = (const int*)d_in[7];
  const int* s_r_conn = (const int*)d_in[8];
  const int* s_r_deg  = (const int*)d_in[9];
  const float* emb      = (const float*)d_in[10];
  const float* gcn_w    = (const float*)d_in[11];
  const float* gcn_bias = (const float*)d_in[12];
  const float* proj1_w  = (const float*)d_in[13];
  const float* proj1_b  = (const float*)d_in[14];
  const float* proj2_w  = (const float*)d_in[15];
  const float* proj2_b  = (const float*)d_in[16];
  const float* ln_g     = (const float*)d_in[17];
  const float* ln_b     = (const float*)d_in[18];
  const float* w_ih     = (const float*)d_in[19];
  const float* w_hh     = (const float*)d_in[20];
  const float* b_ih     = (const float*)d_in[21];
  const float* b_hh     = (const float*)d_in[22];

  float* ws = (float*)d_ws;
  float* qnb   = ws + WS_QNB;
  float* Z     = ws + WS_Z;
  float* qg    = ws + WS_QG;
  ushortT* xwb = (ushortT*)(ws + WS_XW);
  float* cbuf  = ws + WS_CBUF;
  ushortT* XS    = (ushortT*)(ws + WS_XS);
  ushortT* h1b   = (ushortT*)(ws + WS_H1B);
  ushortT* abf   = (ushortT*)(ws + WS_ABF);
  ushortT* hb1   = (ushortT*)(ws + WS_HB1);
  ushortT* p1b16 = (ushortT*)(ws + WS_P1B);
  ushortT* p2b16 = (ushortT*)(ws + WS_P2B);
  ushortT* wihb  = (ushortT*)(ws + WS_WIHB);
  ushortT* whhb  = (ushortT*)(ws + WS_WHHB);
  ushortT* gwb   = (ushortT*)(ws + WS_GWB);
  float* snb   = ws + WS_SNB;
  float* h1g   = ws + WS_H1G;
  float* zb    = ws + WS_ZB;
  float* sg    = ws + WS_SG;
  float* sn    = ws + WS_SN;
  float* sWl   = ws + WS_SWL;
  float* bL    = ws + WS_BL;
  ushortT* emb16 = (ushortT*)(ws + WS_EMB16);
  float* out   = (float*)d_out;

  const size_t needF = (size_t)WS_EMB16 + (EMB_ELEMS + 1) / 2;
  const int useBf16 = (ws_size >= needF * sizeof(float)) ? 1 : 0;

  hipLaunchKernelGGL(k_prep, dim3(2048), dim3(256), 0, stream,
                     emb, emb16, useBf16,
                     w_ih, w_hh, proj1_w, proj2_w, gcn_w, b_ih, b_hh,
                     p1b16, p2b16, wihb, whhb, gwb, bL);
  if (useBf16) {
    hipLaunchKernelGGL(k_gather16, dim3(2 * (BQ + NS)), dim3(256), 0, stream,
                       q_l_conn, q_r_conn, s_l_conn, s_r_conn, emb16, XS);
  } else {
    hipLaunchKernelGGL(k_gather32, dim3(2 * (BQ + NS)), dim3(256), 0, stream,
                       q_l_conn, q_r_conn, s_l_conn, s_r_conn, emb, XS);
  }
  hipLaunchKernelGGL(k_gcn, dim3(129), dim3(256), 0, stream,
                     XS, gwb, gcn_bias, q_l_deg, q_r_deg, s_l_deg, s_r_deg,
                     qnb, snb, abf);
  hipLaunchKernelGGL(k_proj1, dim3(256 + 640), dim3(256), 0, stream,
                     abf, p1b16, proj1_b, h1b,
                     snb, proj1_w, proj1_b, h1g);
  hipLaunchKernelGGL(k_proj2, dim3(128 + 320), dim3(256), 0, stream,
                     h1b, p2b16, proj2_b, qnb, Z,
                     snb, h1g, proj2_w, proj2_b, zb);
  hipLaunchKernelGGL(k_ln2, dim3(BQ / 4 + 1), dim3(256), 0, stream,
                     Z, ln_g, ln_b, qg, abf, zb, sg, sn);
  hipLaunchKernelGGL(k_gemm_lstm, dim3(512 + 256), dim3(256), 0, stream,
                     abf, wihb, bL, sWl, qg, xwb, cbuf, hb1, sg, w_hh, 0);
  hipLaunchKernelGGL(k_gemm_lstm, dim3(512), dim3(256), 0, stream,
                     hb1, whhb, bL, sWl, qg, xwb, cbuf, abf, sg, w_hh, 1);
  hipLaunchKernelGGL(k_gemm_lstm, dim3(512), dim3(256), 0, stream,
                     abf, whhb, bL, sWl, qg, xwb, cbuf, hb1, sg, w_hh, 1);
  hipLaunchKernelGGL(k_gemm_lstm, dim3(512), dim3(256), 0, stream,
                     hb1, whhb, bL, sWl, qg, xwb, cbuf, (ushortT*)nullptr, sg, w_hh, 2);
  hipLaunchKernelGGL(k_out, dim3(BQ / 4), dim3(256), 0, stream, cbuf, sn, out);
}